// Round 6
// baseline (428.220 us; speedup 1.0000x reference)
//
#include <hip/hip_runtime.h>
#include <hip/hip_bf16.h>
#include <cstdint>

// MoE 16384x1024, d_int=512, 8 experts, top-2.
// Round 6: BK=64 + G4 XOR LDS swizzle (pre-swizzled gl16 source, rule #21) kills the
// 8-way ds_read_b128 bank conflict; exact grids via scan2-built tile lists (no dead blocks).

#define NT 16384
#define DM 1024
#define DI 512
#define NE 8
#define NB 16     // (j,e) buckets
#define HB 64     // histogram blocks (256 tokens each)
#define MAXT1 272 // max fc1 m-tiles: 32768/128 + 16
#define MAXT2 136 // max fc2 m-tiles per pass: 16384/128 + 8

typedef __attribute__((ext_vector_type(8))) short bf16x8;
typedef __attribute__((ext_vector_type(4))) float f32x4;

__device__ __forceinline__ void gl16(const void* g, void* l) {
  __builtin_amdgcn_global_load_lds(
      (const __attribute__((address_space(1))) void*)g,
      (__attribute__((address_space(3))) void*)l, 16, 0, 0);
}

__device__ __forceinline__ ushort f2bf(float f) {
  uint32_t x = __float_as_uint(f);
  return (ushort)((x + 0x7fffu + ((x >> 16) & 1u)) >> 16);  // RNE, finite inputs
}

// ---------------- fp32 -> bf16 convert (weights only; x fused into gate) ----------------
__global__ __launch_bounds__(256) void f2bf_kernel(const float* __restrict__ in,
                                                   ushort* __restrict__ out, int n8) {
  int i = blockIdx.x * 256 + threadIdx.x;
  if (i >= n8) return;
  const float4* p = (const float4*)(in + (size_t)i * 8);
  float4 a = p[0], b = p[1];
  union { ushort u[8]; int4 v; } o;
  o.u[0] = f2bf(a.x); o.u[1] = f2bf(a.y); o.u[2] = f2bf(a.z); o.u[3] = f2bf(a.w);
  o.u[4] = f2bf(b.x); o.u[5] = f2bf(b.y); o.u[6] = f2bf(b.z); o.u[7] = f2bf(b.w);
  *(int4*)(out + (size_t)i * 8) = o.v;
}

// ---------------- gate: scores -> top2 -> renorm; fused x->bf16. NO atomics. ----------------
__global__ __launch_bounds__(256) void gate_kernel(
    const float* __restrict__ x, const float* __restrict__ wg,
    int* __restrict__ topk_idx, float* __restrict__ topk_w,
    ushort* __restrict__ xb) {
  __shared__ float wgs[NE * DM];
  for (int i = threadIdx.x; i < NE * DM; i += 256) wgs[i] = wg[i];
  __syncthreads();
  const int wave = threadIdx.x >> 6;
  const int lane = threadIdx.x & 63;
  const int wid = blockIdx.x * 4 + wave;
  for (int g = 0; g < 4; ++g) {
    const int t = wid * 4 + g;
    const float* __restrict__ xr = x + (size_t)t * DM;
    ushort* __restrict__ xw = xb + (size_t)t * DM;
    float acc[NE];
#pragma unroll
    for (int e = 0; e < NE; ++e) acc[e] = 0.f;
#pragma unroll
    for (int it = 0; it < DM / 64; ++it) {
      int k = lane + it * 64;
      float xv = xr[k];
      xw[k] = f2bf(xv);
#pragma unroll
      for (int e = 0; e < NE; ++e) acc[e] += xv * wgs[e * DM + k];
    }
#pragma unroll
    for (int e = 0; e < NE; ++e) {
      float v = acc[e];
#pragma unroll
      for (int off = 32; off > 0; off >>= 1) v += __shfl_xor(v, off);
      acc[e] = v;
    }
    if (lane == 0) {
      float mx = acc[0];
#pragma unroll
      for (int e = 1; e < NE; ++e) mx = fmaxf(mx, acc[e]);
      float p[NE];
#pragma unroll
      for (int e = 0; e < NE; ++e) p[e] = __expf(acc[e] - mx);
      int i0 = 0;
#pragma unroll
      for (int e = 1; e < NE; ++e) if (p[e] > p[i0]) i0 = e;
      int i1 = -1;
#pragma unroll
      for (int e = 0; e < NE; ++e) if (e != i0 && (i1 < 0 || p[e] > p[i1])) i1 = e;
      float s = p[i0] + p[i1];
      topk_idx[t * 2 + 0] = i0;
      topk_idx[t * 2 + 1] = i1;
      topk_w[t * 2 + 0] = p[i0] / s;
      topk_w[t * 2 + 1] = p[i1] / s;
    }
  }
}

// ---------------- hist: per-block bucket counts (LDS atomics only) ----------------
__global__ __launch_bounds__(256) void hist_kernel(const int* __restrict__ topk_idx,
                                                   int* __restrict__ blkcnt) {
  __shared__ int lc[NB];
  if (threadIdx.x < NB) lc[threadIdx.x] = 0;
  __syncthreads();
  int t = blockIdx.x * 256 + threadIdx.x;
  atomicAdd(&lc[topk_idx[t * 2 + 0]], 1);
  atomicAdd(&lc[8 + topk_idx[t * 2 + 1]], 1);
  __syncthreads();
  if (threadIdx.x < NB) blkcnt[blockIdx.x * NB + threadIdx.x] = lc[threadIdx.x];
}

// ---------------- scan2: totals, offsets, per-block bases, tile lists ----------------
__global__ void scan2_kernel(const int* __restrict__ blkcnt, int* __restrict__ counts,
                             int* __restrict__ offsets, int* __restrict__ blk_base,
                             int* __restrict__ t1_list, int* __restrict__ t2_list,
                             int* __restrict__ nmeta) {
  __shared__ int tot[NB], offs[NB];
  const int i = threadIdx.x;
  if (i < NB) {
    int s = 0;
    for (int b = 0; b < HB; ++b) s += blkcnt[b * NB + i];
    tot[i] = s;
    counts[i] = s;
  }
  __syncthreads();
  if (i == 0) {
    int o = 0;
    for (int b = 0; b < NB; ++b) { offs[b] = o; offsets[b] = o; o += tot[b]; }
  }
  __syncthreads();
  if (i < NB) {
    int o = offs[i];
    for (int b = 0; b < HB; ++b) { blk_base[b * NB + i] = o; o += blkcnt[b * NB + i]; }
  }
  if (i == 0) {
    int n1 = 0;
    for (int b = 0; b < NB; ++b) {
      int mts = (tot[b] + 127) >> 7;
      for (int mt = 0; mt < mts; ++mt) t1_list[n1++] = (b << 8) | mt;
    }
    nmeta[0] = n1;
    int n2 = 0;
    for (int b = 0; b < 8; ++b) {
      int mts = (tot[b] + 127) >> 7;
      for (int mt = 0; mt < mts; ++mt) t2_list[n2++] = (b << 8) | mt;
    }
    nmeta[1] = n2;
    int n3 = 0;
    for (int b = 8; b < NB; ++b) {
      int mts = (tot[b] + 127) >> 7;
      for (int mt = 0; mt < mts; ++mt) t2_list[MAXT2 + n3++] = (b << 8) | mt;
    }
    nmeta[2] = n3;
  }
}

// ---------------- fill: LDS cursors + precomputed bases. NO global atomics. ----------------
__global__ __launch_bounds__(256) void fill_kernel(
    const int* __restrict__ topk_idx, const float* __restrict__ topk_w,
    const int* __restrict__ blk_base, int* __restrict__ bucket_tok,
    float* __restrict__ bucket_w) {
  __shared__ int lcur[NB];
  if (threadIdx.x < NB) lcur[threadIdx.x] = 0;
  __syncthreads();
  int t = blockIdx.x * 256 + threadIdx.x;
#pragma unroll
  for (int j = 0; j < 2; ++j) {
    int e = topk_idx[t * 2 + j];
    int b = j * 8 + e;
    int pos = atomicAdd(&lcur[b], 1);
    int slot = blk_base[blockIdx.x * NB + b] + pos;
    bucket_tok[slot] = t;
    bucket_w[slot] = topk_w[t * 2 + j];
  }
}

// ---------------- fc1 + swiglu: tile 128 tok x 64 zcols, BK=64, swizzled LDS ----------------
__global__ __launch_bounds__(256) void fc1_kernel(
    const ushort* __restrict__ xb, const ushort* __restrict__ fc1b,
    const int* __restrict__ counts, const int* __restrict__ offsets,
    const int* __restrict__ bucket_tok, const int* __restrict__ t1_list,
    const int* __restrict__ nmeta, ushort* __restrict__ z) {
  const int tl = blockIdx.x >> 3;
  if (tl >= nmeta[0]) return;
  const int nt = blockIdx.x & 7;
  const int d = t1_list[tl];
  const int b = d >> 8, mt = d & 255;
  const int cnt = counts[b], off = offsets[b], e = b & 7;
  const int m0 = mt << 7, n0 = nt << 6;

  __shared__ ushort As[128 * 64];   // 16KB, rows of 128B
  __shared__ ushort By[64 * 64];    // 8KB
  __shared__ ushort Bg[64 * 64];    // 8KB
  __shared__ int toks[128];

  const int t = threadIdx.x;
  if (t < 128) {
    int m = m0 + t;
    toks[t] = bucket_tok[off + ((m < cnt) ? m : (cnt - 1))];
  }
  __syncthreads();

  // staging: thread t covers LDS row rA=t>>3 (+32/round), source chunk pre-swizzled (rule #21)
  const int rA = t >> 3;
  const int g8 = (((t & 7) ^ (rA & 7)) << 3);   // swizzled 16B-chunk, in ushorts
  const int wave = t >> 6, lane = t & 63;

  const ushort* aSrc0 = xb + (size_t)toks[rA] * DM + g8;
  const ushort* aSrc1 = xb + (size_t)toks[32 + rA] * DM + g8;
  const ushort* aSrc2 = xb + (size_t)toks[64 + rA] * DM + g8;
  const ushort* aSrc3 = xb + (size_t)toks[96 + rA] * DM + g8;
  const ushort* fe = fc1b + (size_t)e * (2 * DI) * DM;
  const ushort* ySrc0 = fe + (size_t)(n0 + rA) * DM + g8;
  const ushort* ySrc1 = fe + (size_t)(n0 + 32 + rA) * DM + g8;
  const ushort* gSrc0 = fe + (size_t)(DI + n0 + rA) * DM + g8;
  const ushort* gSrc1 = fe + (size_t)(DI + n0 + 32 + rA) * DM + g8;

  char* AsW = (char*)As + wave * 1024;
  char* ByW = (char*)By + wave * 1024;
  char* BgW = (char*)Bg + wave * 1024;

  // fragment reads: row = moff/noff + 16i + fr; chunk c = (ks*4+fg) ^ (fr&7)
  const int moff = (wave >> 1) * 64, noff = (wave & 1) * 32;
  const int fr = lane & 15, fg = lane >> 4;
  const int c0 = ((fg ^ (fr & 7)) << 4);          // ks=0, bytes
  const int c1 = (((4 + fg) ^ (fr & 7)) << 4);    // ks=1
  const char* aRd = (const char*)As + (moff + fr) * 128;
  const char* yRd = (const char*)By + (noff + fr) * 128;
  const char* gRd = (const char*)Bg + (noff + fr) * 128;

  f32x4 accY[4][2], accG[4][2];
#pragma unroll
  for (int i = 0; i < 4; ++i)
#pragma unroll
    for (int j = 0; j < 2; ++j) { accY[i][j] = (f32x4)0.f; accG[i][j] = (f32x4)0.f; }

  for (int k0 = 0; k0 < DM; k0 += 64) {
    gl16(aSrc0 + k0, AsW);
    gl16(aSrc1 + k0, AsW + 4096);
    gl16(aSrc2 + k0, AsW + 8192);
    gl16(aSrc3 + k0, AsW + 12288);
    gl16(ySrc0 + k0, ByW);
    gl16(ySrc1 + k0, ByW + 4096);
    gl16(gSrc0 + k0, BgW);
    gl16(gSrc1 + k0, BgW + 4096);
    __syncthreads();
#pragma unroll
    for (int ks = 0; ks < 2; ++ks) {
      const int cc = ks ? c1 : c0;
      bf16x8 a0 = *(const bf16x8*)(aRd + 0 * 2048 + cc);
      bf16x8 a1 = *(const bf16x8*)(aRd + 1 * 2048 + cc);
      bf16x8 a2 = *(const bf16x8*)(aRd + 2 * 2048 + cc);
      bf16x8 a3 = *(const bf16x8*)(aRd + 3 * 2048 + cc);
      bf16x8 y0 = *(const bf16x8*)(yRd + 0 * 2048 + cc);
      bf16x8 y1 = *(const bf16x8*)(yRd + 1 * 2048 + cc);
      bf16x8 g0 = *(const bf16x8*)(gRd + 0 * 2048 + cc);
      bf16x8 g1 = *(const bf16x8*)(gRd + 1 * 2048 + cc);
      accY[0][0] = __builtin_amdgcn_mfma_f32_16x16x32_bf16(a0, y0, accY[0][0], 0, 0, 0);
      accY[1][0] = __builtin_amdgcn_mfma_f32_16x16x32_bf16(a1, y0, accY[1][0], 0, 0, 0);
      accY[2][0] = __builtin_amdgcn_mfma_f32_16x16x32_bf16(a2, y0, accY[2][0], 0, 0, 0);
      accY[3][0] = __builtin_amdgcn_mfma_f32_16x16x32_bf16(a3, y0, accY[3][0], 0, 0, 0);
      accY[0][1] = __builtin_amdgcn_mfma_f32_16x16x32_bf16(a0, y1, accY[0][1], 0, 0, 0);
      accY[1][1] = __builtin_amdgcn_mfma_f32_16x16x32_bf16(a1, y1, accY[1][1], 0, 0, 0);
      accY[2][1] = __builtin_amdgcn_mfma_f32_16x16x32_bf16(a2, y1, accY[2][1], 0, 0, 0);
      accY[3][1] = __builtin_amdgcn_mfma_f32_16x16x32_bf16(a3, y1, accY[3][1], 0, 0, 0);
      accG[0][0] = __builtin_amdgcn_mfma_f32_16x16x32_bf16(a0, g0, accG[0][0], 0, 0, 0);
      accG[1][0] = __builtin_amdgcn_mfma_f32_16x16x32_bf16(a1, g0, accG[1][0], 0, 0, 0);
      accG[2][0] = __builtin_amdgcn_mfma_f32_16x16x32_bf16(a2, g0, accG[2][0], 0, 0, 0);
      accG[3][0] = __builtin_amdgcn_mfma_f32_16x16x32_bf16(a3, g0, accG[3][0], 0, 0, 0);
      accG[0][1] = __builtin_amdgcn_mfma_f32_16x16x32_bf16(a0, g1, accG[0][1], 0, 0, 0);
      accG[1][1] = __builtin_amdgcn_mfma_f32_16x16x32_bf16(a1, g1, accG[1][1], 0, 0, 0);
      accG[2][1] = __builtin_amdgcn_mfma_f32_16x16x32_bf16(a2, g1, accG[2][1], 0, 0, 0);
      accG[3][1] = __builtin_amdgcn_mfma_f32_16x16x32_bf16(a3, g1, accG[3][1], 0, 0, 0);
    }
    __syncthreads();
  }

#pragma unroll
  for (int i = 0; i < 4; ++i)
#pragma unroll
    for (int r = 0; r < 4; ++r) {
      int m = moff + i * 16 + fg * 4 + r;
      if (m0 + m < cnt) {
        ushort* zrow = z + (size_t)(off + m0 + m) * DI + n0 + noff + fr;
#pragma unroll
        for (int j = 0; j < 2; ++j) {
          float y = accY[i][j][r], g = accG[i][j][r];
          float zz = y * g / (1.f + __expf(-g));
          zrow[j * 16] = f2bf(zz);
        }
      }
    }
}

// ---------------- fc2: out[tok] (=|+=) w * (z @ fc2[e].T), tile 128x128, BK=64 ----------------
template <bool ADD>
__global__ __launch_bounds__(256) void fc2_kernel(
    const ushort* __restrict__ z, const ushort* __restrict__ fc2b,
    const int* __restrict__ counts, const int* __restrict__ offsets,
    const int* __restrict__ bucket_tok, const float* __restrict__ bucket_w,
    const int* __restrict__ t2_list, const int* __restrict__ nmeta,
    float* __restrict__ out) {
  const int tl = blockIdx.x >> 3;
  if (tl >= nmeta[ADD ? 2 : 1]) return;
  const int nt = blockIdx.x & 7;
  const int d = t2_list[(ADD ? MAXT2 : 0) + tl];
  const int b = d >> 8, mt = d & 255;
  const int cnt = counts[b], off = offsets[b], e = b & 7;
  const int m0 = mt << 7, n0 = nt << 7;

  __shared__ ushort As[128 * 64];
  __shared__ ushort Bs[128 * 64];
  __shared__ int toks[128];
  __shared__ float wts[128];

  const int t = threadIdx.x;
  if (t < 128) {
    int m = m0 + t;
    int mm = (m < cnt) ? m : (cnt - 1);
    toks[t] = bucket_tok[off + mm];
    wts[t] = bucket_w[off + mm];
  }
  __syncthreads();

  const int rA = t >> 3;
  const int g8 = (((t & 7) ^ (rA & 7)) << 3);
  const int wave = t >> 6, lane = t & 63;

  const ushort* aSrc0 = z + (size_t)(off + m0 + rA) * DI + g8;
  const ushort* fb = fc2b + (size_t)e * DM * DI;
  const ushort* bSrc0 = fb + (size_t)(n0 + rA) * DI + g8;

  char* AsW = (char*)As + wave * 1024;
  char* BsW = (char*)Bs + wave * 1024;

  const int moff = (wave >> 1) * 64, noff = (wave & 1) * 64;
  const int fr = lane & 15, fg = lane >> 4;
  const int c0 = ((fg ^ (fr & 7)) << 4);
  const int c1 = (((4 + fg) ^ (fr & 7)) << 4);
  const char* aRd = (const char*)As + (moff + fr) * 128;
  const char* bRd = (const char*)Bs + (noff + fr) * 128;

  f32x4 acc[4][4];
#pragma unroll
  for (int i = 0; i < 4; ++i)
#pragma unroll
    for (int j = 0; j < 4; ++j) acc[i][j] = (f32x4)0.f;

  for (int k0 = 0; k0 < DI; k0 += 64) {
    gl16(aSrc0 + k0, AsW);
    gl16(aSrc0 + (size_t)32 * DI + k0, AsW + 4096);
    gl16(aSrc0 + (size_t)64 * DI + k0, AsW + 8192);
    gl16(aSrc0 + (size_t)96 * DI + k0, AsW + 12288);
    gl16(bSrc0 + k0, BsW);
    gl16(bSrc0 + (size_t)32 * DI + k0, BsW + 4096);
    gl16(bSrc0 + (size_t)64 * DI + k0, BsW + 8192);
    gl16(bSrc0 + (size_t)96 * DI + k0, BsW + 12288);
    __syncthreads();
#pragma unroll
    for (int ks = 0; ks < 2; ++ks) {
      const int cc = ks ? c1 : c0;
      bf16x8 a0 = *(const bf16x8*)(aRd + 0 * 2048 + cc);
      bf16x8 a1 = *(const bf16x8*)(aRd + 1 * 2048 + cc);
      bf16x8 a2 = *(const bf16x8*)(aRd + 2 * 2048 + cc);
      bf16x8 a3 = *(const bf16x8*)(aRd + 3 * 2048 + cc);
      bf16x8 b0 = *(const bf16x8*)(bRd + 0 * 2048 + cc);
      bf16x8 b1 = *(const bf16x8*)(bRd + 1 * 2048 + cc);
      bf16x8 b2 = *(const bf16x8*)(bRd + 2 * 2048 + cc);
      bf16x8 b3 = *(const bf16x8*)(bRd + 3 * 2048 + cc);
#pragma unroll
      for (int i = 0; i < 4; ++i) {
        bf16x8 ai = (i == 0) ? a0 : (i == 1) ? a1 : (i == 2) ? a2 : a3;
        acc[i][0] = __builtin_amdgcn_mfma_f32_16x16x32_bf16(ai, b0, acc[i][0], 0, 0, 0);
        acc[i][1] = __builtin_amdgcn_mfma_f32_16x16x32_bf16(ai, b1, acc[i][1], 0, 0, 0);
        acc[i][2] = __builtin_amdgcn_mfma_f32_16x16x32_bf16(ai, b2, acc[i][2], 0, 0, 0);
        acc[i][3] = __builtin_amdgcn_mfma_f32_16x16x32_bf16(ai, b3, acc[i][3], 0, 0, 0);
      }
    }
    __syncthreads();
  }

#pragma unroll
  for (int i = 0; i < 4; ++i)
#pragma unroll
    for (int r = 0; r < 4; ++r) {
      int m = moff + i * 16 + fg * 4 + r;
      if (m0 + m < cnt) {
        int tok = toks[m];
        float w = wts[m];
        float* orow = out + (size_t)tok * DM + n0 + noff + fr;
#pragma unroll
        for (int j = 0; j < 4; ++j) {
          float v = w * acc[i][j][r];
          if (ADD) orow[j * 16] += v;
          else     orow[j * 16] = v;
        }
      }
    }
}

// ---------------- launch ----------------
extern "C" void kernel_launch(void* const* d_in, const int* in_sizes, int n_in,
                              void* d_out, int out_size, void* d_ws, size_t ws_size,
                              hipStream_t stream) {
  (void)in_sizes; (void)n_in; (void)out_size; (void)ws_size;
  const float* x   = (const float*)d_in[0];
  const float* wg  = (const float*)d_in[1];
  const float* fc1 = (const float*)d_in[2];
  const float* fc2 = (const float*)d_in[3];
  float* out = (float*)d_out;

  char* p = (char*)d_ws;
  ushort* xb   = (ushort*)p; p += (size_t)NT * DM * 2;
  ushort* fc1b = (ushort*)p; p += (size_t)NE * 2 * DI * DM * 2;
  ushort* fc2b = (ushort*)p; p += (size_t)NE * DM * DI * 2;
  ushort* z    = (ushort*)p; p += ((size_t)2 * NT + 128) * DI * 2;
  int*   topk_idx   = (int*)p;   p += (size_t)NT * 2 * 4;
  float* topk_w     = (float*)p; p += (size_t)NT * 2 * 4;
  int*   bucket_tok = (int*)p;   p += (size_t)2 * NT * 4;
  float* bucket_w   = (float*)p; p += (size_t)2 * NT * 4;
  int*   counts     = (int*)p;   p += NB * 4;
  int*   offsets    = (int*)p;   p += NB * 4;
  int*   blkcnt     = (int*)p;   p += HB * NB * 4;
  int*   blk_base   = (int*)p;   p += HB * NB * 4;
  int*   t1_list    = (int*)p;   p += MAXT1 * 4;
  int*   t2_list    = (int*)p;   p += 2 * MAXT2 * 4;
  int*   nmeta      = (int*)p;   p += 4 * 4;

  f2bf_kernel<<<(NE * 2 * DI * DM / 8 + 255) / 256, 256, 0, stream>>>(fc1, fc1b, NE * 2 * DI * DM / 8);
  f2bf_kernel<<<(NE * DM * DI / 8 + 255) / 256, 256, 0, stream>>>(fc2, fc2b, NE * DM * DI / 8);

  gate_kernel<<<1024, 256, 0, stream>>>(x, wg, topk_idx, topk_w, xb);
  hist_kernel<<<HB, 256, 0, stream>>>(topk_idx, blkcnt);
  scan2_kernel<<<1, 64, 0, stream>>>(blkcnt, counts, offsets, blk_base, t1_list, t2_list, nmeta);
  fill_kernel<<<HB, 256, 0, stream>>>(topk_idx, topk_w, blk_base, bucket_tok, bucket_w);

  fc1_kernel<<<MAXT1 * 8, 256, 0, stream>>>(xb, fc1b, counts, offsets, bucket_tok,
                                            t1_list, nmeta, z);
  fc2_kernel<false><<<MAXT2 * 8, 256, 0, stream>>>(z, fc2b, counts, offsets, bucket_tok,
                                                   bucket_w, t2_list, nmeta, out);
  fc2_kernel<true><<<MAXT2 * 8, 256, 0, stream>>>(z, fc2b, counts, offsets, bucket_tok,
                                                  bucket_w, t2_list, nmeta, out);
}

// Round 7
// 418.551 us; speedup vs baseline: 1.0231x; 1.0231x over previous
//
#include <hip/hip_runtime.h>
#include <hip/hip_bf16.h>
#include <cstdint>

// MoE 16384x1024, d_int=512, 8 experts, top-2.
// Round 7: XCD co-scheduling remap (T1): the 8 nt-blocks sharing an A-tile get the same
// blockIdx%8 (same XCD under RR dispatch) within one 64-bid group -> A fetched once/XCD.
// (r6 installed conflict-free swizzled LDS; conflicts=0 but time flat -> T2 regime-gated.)

#define NT 16384
#define DM 1024
#define DI 512
#define NE 8
#define NB 16     // (j,e) buckets
#define HB 64     // histogram blocks (256 tokens each)
#define MAXT1 272 // max fc1 m-tiles (multiple of 8; grid 272*8=2176=34*64)
#define MAXT2 136 // max fc2 m-tiles per pass (multiple of 8; grid 136*8=1088=17*64)

typedef __attribute__((ext_vector_type(8))) short bf16x8;
typedef __attribute__((ext_vector_type(4))) float f32x4;

__device__ __forceinline__ void gl16(const void* g, void* l) {
  __builtin_amdgcn_global_load_lds(
      (const __attribute__((address_space(1))) void*)g,
      (__attribute__((address_space(3))) void*)l, 16, 0, 0);
}

__device__ __forceinline__ ushort f2bf(float f) {
  uint32_t x = __float_as_uint(f);
  return (ushort)((x + 0x7fffu + ((x >> 16) & 1u)) >> 16);  // RNE, finite inputs
}

// ---------------- fp32 -> bf16 convert (weights only; x fused into gate) ----------------
__global__ __launch_bounds__(256) void f2bf_kernel(const float* __restrict__ in,
                                                   ushort* __restrict__ out, int n8) {
  int i = blockIdx.x * 256 + threadIdx.x;
  if (i >= n8) return;
  const float4* p = (const float4*)(in + (size_t)i * 8);
  float4 a = p[0], b = p[1];
  union { ushort u[8]; int4 v; } o;
  o.u[0] = f2bf(a.x); o.u[1] = f2bf(a.y); o.u[2] = f2bf(a.z); o.u[3] = f2bf(a.w);
  o.u[4] = f2bf(b.x); o.u[5] = f2bf(b.y); o.u[6] = f2bf(b.z); o.u[7] = f2bf(b.w);
  *(int4*)(out + (size_t)i * 8) = o.v;
}

// ---------------- gate: scores -> top2 -> renorm; fused x->bf16. NO atomics. ----------------
__global__ __launch_bounds__(256) void gate_kernel(
    const float* __restrict__ x, const float* __restrict__ wg,
    int* __restrict__ topk_idx, float* __restrict__ topk_w,
    ushort* __restrict__ xb) {
  __shared__ float wgs[NE * DM];
  for (int i = threadIdx.x; i < NE * DM; i += 256) wgs[i] = wg[i];
  __syncthreads();
  const int wave = threadIdx.x >> 6;
  const int lane = threadIdx.x & 63;
  const int wid = blockIdx.x * 4 + wave;
  for (int g = 0; g < 4; ++g) {
    const int t = wid * 4 + g;
    const float* __restrict__ xr = x + (size_t)t * DM;
    ushort* __restrict__ xw = xb + (size_t)t * DM;
    float acc[NE];
#pragma unroll
    for (int e = 0; e < NE; ++e) acc[e] = 0.f;
#pragma unroll
    for (int it = 0; it < DM / 64; ++it) {
      int k = lane + it * 64;
      float xv = xr[k];
      xw[k] = f2bf(xv);
#pragma unroll
      for (int e = 0; e < NE; ++e) acc[e] += xv * wgs[e * DM + k];
    }
#pragma unroll
    for (int e = 0; e < NE; ++e) {
      float v = acc[e];
#pragma unroll
      for (int off = 32; off > 0; off >>= 1) v += __shfl_xor(v, off);
      acc[e] = v;
    }
    if (lane == 0) {
      float mx = acc[0];
#pragma unroll
      for (int e = 1; e < NE; ++e) mx = fmaxf(mx, acc[e]);
      float p[NE];
#pragma unroll
      for (int e = 0; e < NE; ++e) p[e] = __expf(acc[e] - mx);
      int i0 = 0;
#pragma unroll
      for (int e = 1; e < NE; ++e) if (p[e] > p[i0]) i0 = e;
      int i1 = -1;
#pragma unroll
      for (int e = 0; e < NE; ++e) if (e != i0 && (i1 < 0 || p[e] > p[i1])) i1 = e;
      float s = p[i0] + p[i1];
      topk_idx[t * 2 + 0] = i0;
      topk_idx[t * 2 + 1] = i1;
      topk_w[t * 2 + 0] = p[i0] / s;
      topk_w[t * 2 + 1] = p[i1] / s;
    }
  }
}

// ---------------- hist: per-block bucket counts (LDS atomics only) ----------------
__global__ __launch_bounds__(256) void hist_kernel(const int* __restrict__ topk_idx,
                                                   int* __restrict__ blkcnt) {
  __shared__ int lc[NB];
  if (threadIdx.x < NB) lc[threadIdx.x] = 0;
  __syncthreads();
  int t = blockIdx.x * 256 + threadIdx.x;
  atomicAdd(&lc[topk_idx[t * 2 + 0]], 1);
  atomicAdd(&lc[8 + topk_idx[t * 2 + 1]], 1);
  __syncthreads();
  if (threadIdx.x < NB) blkcnt[blockIdx.x * NB + threadIdx.x] = lc[threadIdx.x];
}

// ---------------- scan2: totals, offsets, per-block bases, tile lists ----------------
__global__ void scan2_kernel(const int* __restrict__ blkcnt, int* __restrict__ counts,
                             int* __restrict__ offsets, int* __restrict__ blk_base,
                             int* __restrict__ t1_list, int* __restrict__ t2_list,
                             int* __restrict__ nmeta) {
  __shared__ int tot[NB], offs[NB];
  const int i = threadIdx.x;
  if (i < NB) {
    int s = 0;
    for (int b = 0; b < HB; ++b) s += blkcnt[b * NB + i];
    tot[i] = s;
    counts[i] = s;
  }
  __syncthreads();
  if (i == 0) {
    int o = 0;
    for (int b = 0; b < NB; ++b) { offs[b] = o; offsets[b] = o; o += tot[b]; }
  }
  __syncthreads();
  if (i < NB) {
    int o = offs[i];
    for (int b = 0; b < HB; ++b) { blk_base[b * NB + i] = o; o += blkcnt[b * NB + i]; }
  }
  if (i == 0) {
    int n1 = 0;
    for (int b = 0; b < NB; ++b) {
      int mts = (tot[b] + 127) >> 7;
      for (int mt = 0; mt < mts; ++mt) t1_list[n1++] = (b << 8) | mt;
    }
    nmeta[0] = n1;
    int n2 = 0;
    for (int b = 0; b < 8; ++b) {
      int mts = (tot[b] + 127) >> 7;
      for (int mt = 0; mt < mts; ++mt) t2_list[n2++] = (b << 8) | mt;
    }
    nmeta[1] = n2;
    int n3 = 0;
    for (int b = 8; b < NB; ++b) {
      int mts = (tot[b] + 127) >> 7;
      for (int mt = 0; mt < mts; ++mt) t2_list[MAXT2 + n3++] = (b << 8) | mt;
    }
    nmeta[2] = n3;
  }
}

// ---------------- fill: LDS cursors + precomputed bases. NO global atomics. ----------------
__global__ __launch_bounds__(256) void fill_kernel(
    const int* __restrict__ topk_idx, const float* __restrict__ topk_w,
    const int* __restrict__ blk_base, int* __restrict__ bucket_tok,
    float* __restrict__ bucket_w) {
  __shared__ int lcur[NB];
  if (threadIdx.x < NB) lcur[threadIdx.x] = 0;
  __syncthreads();
  int t = blockIdx.x * 256 + threadIdx.x;
#pragma unroll
  for (int j = 0; j < 2; ++j) {
    int e = topk_idx[t * 2 + j];
    int b = j * 8 + e;
    int pos = atomicAdd(&lcur[b], 1);
    int slot = blk_base[blockIdx.x * NB + b] + pos;
    bucket_tok[slot] = t;
    bucket_w[slot] = topk_w[t * 2 + j];
  }
}

// ---------------- fc1 + swiglu: tile 128 tok x 64 zcols, BK=64, swizzled LDS ----------------
__global__ __launch_bounds__(256) void fc1_kernel(
    const ushort* __restrict__ xb, const ushort* __restrict__ fc1b,
    const int* __restrict__ counts, const int* __restrict__ offsets,
    const int* __restrict__ bucket_tok, const int* __restrict__ t1_list,
    const int* __restrict__ nmeta, ushort* __restrict__ z) {
  // XCD co-schedule decode: 8 nt-blocks of a tile share bid%8 (one XCD) within a 64-bid group.
  const int gg = blockIdx.x >> 6;
  const int rr = blockIdx.x & 63;
  const int tl = gg * 8 + (rr & 7);
  const int nt = rr >> 3;
  if (tl >= nmeta[0]) return;
  const int d = t1_list[tl];
  const int b = d >> 8, mt = d & 255;
  const int cnt = counts[b], off = offsets[b], e = b & 7;
  const int m0 = mt << 7, n0 = nt << 6;

  __shared__ ushort As[128 * 64];   // 16KB, rows of 128B
  __shared__ ushort By[64 * 64];    // 8KB
  __shared__ ushort Bg[64 * 64];    // 8KB
  __shared__ int toks[128];

  const int t = threadIdx.x;
  if (t < 128) {
    int m = m0 + t;
    toks[t] = bucket_tok[off + ((m < cnt) ? m : (cnt - 1))];
  }
  __syncthreads();

  // staging: thread t covers LDS row rA=t>>3 (+32/round), source chunk pre-swizzled (rule #21)
  const int rA = t >> 3;
  const int g8 = (((t & 7) ^ (rA & 7)) << 3);   // swizzled 16B-chunk, in ushorts
  const int wave = t >> 6, lane = t & 63;

  const ushort* aSrc0 = xb + (size_t)toks[rA] * DM + g8;
  const ushort* aSrc1 = xb + (size_t)toks[32 + rA] * DM + g8;
  const ushort* aSrc2 = xb + (size_t)toks[64 + rA] * DM + g8;
  const ushort* aSrc3 = xb + (size_t)toks[96 + rA] * DM + g8;
  const ushort* fe = fc1b + (size_t)e * (2 * DI) * DM;
  const ushort* ySrc0 = fe + (size_t)(n0 + rA) * DM + g8;
  const ushort* ySrc1 = fe + (size_t)(n0 + 32 + rA) * DM + g8;
  const ushort* gSrc0 = fe + (size_t)(DI + n0 + rA) * DM + g8;
  const ushort* gSrc1 = fe + (size_t)(DI + n0 + 32 + rA) * DM + g8;

  char* AsW = (char*)As + wave * 1024;
  char* ByW = (char*)By + wave * 1024;
  char* BgW = (char*)Bg + wave * 1024;

  // fragment reads: row = moff/noff + 16i + fr; chunk c = (ks*4+fg) ^ (fr&7)
  const int moff = (wave >> 1) * 64, noff = (wave & 1) * 32;
  const int fr = lane & 15, fg = lane >> 4;
  const int c0 = ((fg ^ (fr & 7)) << 4);          // ks=0, bytes
  const int c1 = (((4 + fg) ^ (fr & 7)) << 4);    // ks=1
  const char* aRd = (const char*)As + (moff + fr) * 128;
  const char* yRd = (const char*)By + (noff + fr) * 128;
  const char* gRd = (const char*)Bg + (noff + fr) * 128;

  f32x4 accY[4][2], accG[4][2];
#pragma unroll
  for (int i = 0; i < 4; ++i)
#pragma unroll
    for (int j = 0; j < 2; ++j) { accY[i][j] = (f32x4)0.f; accG[i][j] = (f32x4)0.f; }

  for (int k0 = 0; k0 < DM; k0 += 64) {
    gl16(aSrc0 + k0, AsW);
    gl16(aSrc1 + k0, AsW + 4096);
    gl16(aSrc2 + k0, AsW + 8192);
    gl16(aSrc3 + k0, AsW + 12288);
    gl16(ySrc0 + k0, ByW);
    gl16(ySrc1 + k0, ByW + 4096);
    gl16(gSrc0 + k0, BgW);
    gl16(gSrc1 + k0, BgW + 4096);
    __syncthreads();
#pragma unroll
    for (int ks = 0; ks < 2; ++ks) {
      const int cc = ks ? c1 : c0;
      bf16x8 a0 = *(const bf16x8*)(aRd + 0 * 2048 + cc);
      bf16x8 a1 = *(const bf16x8*)(aRd + 1 * 2048 + cc);
      bf16x8 a2 = *(const bf16x8*)(aRd + 2 * 2048 + cc);
      bf16x8 a3 = *(const bf16x8*)(aRd + 3 * 2048 + cc);
      bf16x8 y0 = *(const bf16x8*)(yRd + 0 * 2048 + cc);
      bf16x8 y1 = *(const bf16x8*)(yRd + 1 * 2048 + cc);
      bf16x8 g0 = *(const bf16x8*)(gRd + 0 * 2048 + cc);
      bf16x8 g1 = *(const bf16x8*)(gRd + 1 * 2048 + cc);
      accY[0][0] = __builtin_amdgcn_mfma_f32_16x16x32_bf16(a0, y0, accY[0][0], 0, 0, 0);
      accY[1][0] = __builtin_amdgcn_mfma_f32_16x16x32_bf16(a1, y0, accY[1][0], 0, 0, 0);
      accY[2][0] = __builtin_amdgcn_mfma_f32_16x16x32_bf16(a2, y0, accY[2][0], 0, 0, 0);
      accY[3][0] = __builtin_amdgcn_mfma_f32_16x16x32_bf16(a3, y0, accY[3][0], 0, 0, 0);
      accY[0][1] = __builtin_amdgcn_mfma_f32_16x16x32_bf16(a0, y1, accY[0][1], 0, 0, 0);
      accY[1][1] = __builtin_amdgcn_mfma_f32_16x16x32_bf16(a1, y1, accY[1][1], 0, 0, 0);
      accY[2][1] = __builtin_amdgcn_mfma_f32_16x16x32_bf16(a2, y1, accY[2][1], 0, 0, 0);
      accY[3][1] = __builtin_amdgcn_mfma_f32_16x16x32_bf16(a3, y1, accY[3][1], 0, 0, 0);
      accG[0][0] = __builtin_amdgcn_mfma_f32_16x16x32_bf16(a0, g0, accG[0][0], 0, 0, 0);
      accG[1][0] = __builtin_amdgcn_mfma_f32_16x16x32_bf16(a1, g0, accG[1][0], 0, 0, 0);
      accG[2][0] = __builtin_amdgcn_mfma_f32_16x16x32_bf16(a2, g0, accG[2][0], 0, 0, 0);
      accG[3][0] = __builtin_amdgcn_mfma_f32_16x16x32_bf16(a3, g0, accG[3][0], 0, 0, 0);
      accG[0][1] = __builtin_amdgcn_mfma_f32_16x16x32_bf16(a0, g1, accG[0][1], 0, 0, 0);
      accG[1][1] = __builtin_amdgcn_mfma_f32_16x16x32_bf16(a1, g1, accG[1][1], 0, 0, 0);
      accG[2][1] = __builtin_amdgcn_mfma_f32_16x16x32_bf16(a2, g1, accG[2][1], 0, 0, 0);
      accG[3][1] = __builtin_amdgcn_mfma_f32_16x16x32_bf16(a3, g1, accG[3][1], 0, 0, 0);
    }
    __syncthreads();
  }

#pragma unroll
  for (int i = 0; i < 4; ++i)
#pragma unroll
    for (int r = 0; r < 4; ++r) {
      int m = moff + i * 16 + fg * 4 + r;
      if (m0 + m < cnt) {
        ushort* zrow = z + (size_t)(off + m0 + m) * DI + n0 + noff + fr;
#pragma unroll
        for (int j = 0; j < 2; ++j) {
          float y = accY[i][j][r], g = accG[i][j][r];
          float zz = y * g / (1.f + __expf(-g));
          zrow[j * 16] = f2bf(zz);
        }
      }
    }
}

// ---------------- fc2: out[tok] (=|+=) w * (z @ fc2[e].T), tile 128x128, BK=64 ----------------
template <bool ADD>
__global__ __launch_bounds__(256) void fc2_kernel(
    const ushort* __restrict__ z, const ushort* __restrict__ fc2b,
    const int* __restrict__ counts, const int* __restrict__ offsets,
    const int* __restrict__ bucket_tok, const float* __restrict__ bucket_w,
    const int* __restrict__ t2_list, const int* __restrict__ nmeta,
    float* __restrict__ out) {
  const int gg = blockIdx.x >> 6;
  const int rr = blockIdx.x & 63;
  const int tl = gg * 8 + (rr & 7);
  const int nt = rr >> 3;
  if (tl >= nmeta[ADD ? 2 : 1]) return;
  const int d = t2_list[(ADD ? MAXT2 : 0) + tl];
  const int b = d >> 8, mt = d & 255;
  const int cnt = counts[b], off = offsets[b], e = b & 7;
  const int m0 = mt << 7, n0 = nt << 7;

  __shared__ ushort As[128 * 64];
  __shared__ ushort Bs[128 * 64];
  __shared__ int toks[128];
  __shared__ float wts[128];

  const int t = threadIdx.x;
  if (t < 128) {
    int m = m0 + t;
    int mm = (m < cnt) ? m : (cnt - 1);
    toks[t] = bucket_tok[off + mm];
    wts[t] = bucket_w[off + mm];
  }
  __syncthreads();

  const int rA = t >> 3;
  const int g8 = (((t & 7) ^ (rA & 7)) << 3);
  const int wave = t >> 6, lane = t & 63;

  const ushort* aSrc0 = z + (size_t)(off + m0 + rA) * DI + g8;
  const ushort* fb = fc2b + (size_t)e * DM * DI;
  const ushort* bSrc0 = fb + (size_t)(n0 + rA) * DI + g8;

  char* AsW = (char*)As + wave * 1024;
  char* BsW = (char*)Bs + wave * 1024;

  const int moff = (wave >> 1) * 64, noff = (wave & 1) * 64;
  const int fr = lane & 15, fg = lane >> 4;
  const int c0 = ((fg ^ (fr & 7)) << 4);
  const int c1 = (((4 + fg) ^ (fr & 7)) << 4);
  const char* aRd = (const char*)As + (moff + fr) * 128;
  const char* bRd = (const char*)Bs + (noff + fr) * 128;

  f32x4 acc[4][4];
#pragma unroll
  for (int i = 0; i < 4; ++i)
#pragma unroll
    for (int j = 0; j < 4; ++j) acc[i][j] = (f32x4)0.f;

  for (int k0 = 0; k0 < DI; k0 += 64) {
    gl16(aSrc0 + k0, AsW);
    gl16(aSrc0 + (size_t)32 * DI + k0, AsW + 4096);
    gl16(aSrc0 + (size_t)64 * DI + k0, AsW + 8192);
    gl16(aSrc0 + (size_t)96 * DI + k0, AsW + 12288);
    gl16(bSrc0 + k0, BsW);
    gl16(bSrc0 + (size_t)32 * DI + k0, BsW + 4096);
    gl16(bSrc0 + (size_t)64 * DI + k0, BsW + 8192);
    gl16(bSrc0 + (size_t)96 * DI + k0, BsW + 12288);
    __syncthreads();
#pragma unroll
    for (int ks = 0; ks < 2; ++ks) {
      const int cc = ks ? c1 : c0;
      bf16x8 a0 = *(const bf16x8*)(aRd + 0 * 2048 + cc);
      bf16x8 a1 = *(const bf16x8*)(aRd + 1 * 2048 + cc);
      bf16x8 a2 = *(const bf16x8*)(aRd + 2 * 2048 + cc);
      bf16x8 a3 = *(const bf16x8*)(aRd + 3 * 2048 + cc);
      bf16x8 b0 = *(const bf16x8*)(bRd + 0 * 2048 + cc);
      bf16x8 b1 = *(const bf16x8*)(bRd + 1 * 2048 + cc);
      bf16x8 b2 = *(const bf16x8*)(bRd + 2 * 2048 + cc);
      bf16x8 b3 = *(const bf16x8*)(bRd + 3 * 2048 + cc);
#pragma unroll
      for (int i = 0; i < 4; ++i) {
        bf16x8 ai = (i == 0) ? a0 : (i == 1) ? a1 : (i == 2) ? a2 : a3;
        acc[i][0] = __builtin_amdgcn_mfma_f32_16x16x32_bf16(ai, b0, acc[i][0], 0, 0, 0);
        acc[i][1] = __builtin_amdgcn_mfma_f32_16x16x32_bf16(ai, b1, acc[i][1], 0, 0, 0);
        acc[i][2] = __builtin_amdgcn_mfma_f32_16x16x32_bf16(ai, b2, acc[i][2], 0, 0, 0);
        acc[i][3] = __builtin_amdgcn_mfma_f32_16x16x32_bf16(ai, b3, acc[i][3], 0, 0, 0);
      }
    }
    __syncthreads();
  }

#pragma unroll
  for (int i = 0; i < 4; ++i)
#pragma unroll
    for (int r = 0; r < 4; ++r) {
      int m = moff + i * 16 + fg * 4 + r;
      if (m0 + m < cnt) {
        int tok = toks[m];
        float w = wts[m];
        float* orow = out + (size_t)tok * DM + n0 + noff + fr;
#pragma unroll
        for (int j = 0; j < 4; ++j) {
          float v = w * acc[i][j][r];
          if (ADD) orow[j * 16] += v;
          else     orow[j * 16] = v;
        }
      }
    }
}

// ---------------- launch ----------------
extern "C" void kernel_launch(void* const* d_in, const int* in_sizes, int n_in,
                              void* d_out, int out_size, void* d_ws, size_t ws_size,
                              hipStream_t stream) {
  (void)in_sizes; (void)n_in; (void)out_size; (void)ws_size;
  const float* x   = (const float*)d_in[0];
  const float* wg  = (const float*)d_in[1];
  const float* fc1 = (const float*)d_in[2];
  const float* fc2 = (const float*)d_in[3];
  float* out = (float*)d_out;

  char* p = (char*)d_ws;
  ushort* xb   = (ushort*)p; p += (size_t)NT * DM * 2;
  ushort* fc1b = (ushort*)p; p += (size_t)NE * 2 * DI * DM * 2;
  ushort* fc2b = (ushort*)p; p += (size_t)NE * DM * DI * 2;
  ushort* z    = (ushort*)p; p += ((size_t)2 * NT + 128) * DI * 2;
  int*   topk_idx   = (int*)p;   p += (size_t)NT * 2 * 4;
  float* topk_w     = (float*)p; p += (size_t)NT * 2 * 4;
  int*   bucket_tok = (int*)p;   p += (size_t)2 * NT * 4;
  float* bucket_w   = (float*)p; p += (size_t)2 * NT * 4;
  int*   counts     = (int*)p;   p += NB * 4;
  int*   offsets    = (int*)p;   p += NB * 4;
  int*   blkcnt     = (int*)p;   p += HB * NB * 4;
  int*   blk_base   = (int*)p;   p += HB * NB * 4;
  int*   t1_list    = (int*)p;   p += MAXT1 * 4;
  int*   t2_list    = (int*)p;   p += 2 * MAXT2 * 4;
  int*   nmeta      = (int*)p;   p += 4 * 4;

  f2bf_kernel<<<(NE * 2 * DI * DM / 8 + 255) / 256, 256, 0, stream>>>(fc1, fc1b, NE * 2 * DI * DM / 8);
  f2bf_kernel<<<(NE * DM * DI / 8 + 255) / 256, 256, 0, stream>>>(fc2, fc2b, NE * DM * DI / 8);

  gate_kernel<<<1024, 256, 0, stream>>>(x, wg, topk_idx, topk_w, xb);
  hist_kernel<<<HB, 256, 0, stream>>>(topk_idx, blkcnt);
  scan2_kernel<<<1, 64, 0, stream>>>(blkcnt, counts, offsets, blk_base, t1_list, t2_list, nmeta);
  fill_kernel<<<HB, 256, 0, stream>>>(topk_idx, topk_w, blk_base, bucket_tok, bucket_w);

  fc1_kernel<<<MAXT1 * 8, 256, 0, stream>>>(xb, fc1b, counts, offsets, bucket_tok,
                                            t1_list, nmeta, z);
  fc2_kernel<false><<<MAXT2 * 8, 256, 0, stream>>>(z, fc2b, counts, offsets, bucket_tok,
                                                   bucket_w, t2_list, nmeta, out);
  fc2_kernel<true><<<MAXT2 * 8, 256, 0, stream>>>(z, fc2b, counts, offsets, bucket_tok,
                                                  bucket_w, t2_list, nmeta, out);
}